// Round 6
// baseline (171.092 us; speedup 1.0000x reference)
//
#include <hip/hip_runtime.h>

// ---------------------------------------------------------------------------
// PreferencePredictor: logits[m] over M=131072 candidates.
// Heavy op: l = llm @ Wl^T (M=131072, K=768, N=256) -> HBM-bound (403 MB).
// Attention over 2 ctx rows collapses to 4 sigmoid gates + rank-4 update with
// precomputed wsd/csd/base/delta (prep kernels).
// Main loop (column-split waves): wave w owns all 64 rows x cols [w*64,w*64+64).
//   - A (8 KB fp32/step) staged via global_load_lds into ring-3 LDS, XOR
//     swizzle (row&7)<<4 (linear dest + inverse-swizzled global src).
//   - B fragments live in REGISTERS, loaded per step from L2 (4 x dwordx4 per
//     wave), double-buffered b0/b1. No B LDS round-trip.
//   - Per step: VMCNT(2) [A(kk+1) stays in flight] -> s_barrier ->
//     sched_barrier(0) [pin stage below barrier] -> issue B(kk+1)+A(kk+2) ->
//     8 ds_read + 16 MFMA. One barrier/step; vmcnt never 0 until tail.
// ws float layout:
//   [0,256) u   [256,512) qv   [512,768) k0  [768,1024) k1
//   [1024,1280) v0  [1280,1536) v1
//   [1536,2560) wsd[4][256]   [2560,2816) base[256]
//   [2816,3840) delta[4][256] [3840,3844) csd[4]
//   float idx 4096: Bs bf16 fragment order Bs[kk(24)][nt(16)][lane(64)][i(8)]
// ---------------------------------------------------------------------------

typedef float f32x4 __attribute__((ext_vector_type(4)));
typedef __bf16 bf16x8 __attribute__((ext_vector_type(8)));

#define VMCNT(n) asm volatile("s_waitcnt vmcnt(" #n ")" ::: "memory")

__device__ __forceinline__ unsigned f2bf(float f) {
  unsigned u = __builtin_bit_cast(unsigned, f);
  u += 0x7fffu + ((u >> 16) & 1u);   // round-to-nearest-even
  return u >> 16;
}

__device__ __forceinline__ void gl_lds16(const void* g, void* l) {
  __builtin_amdgcn_global_load_lds(
      (const __attribute__((address_space(1))) void*)g,
      (__attribute__((address_space(3))) void*)l, 16, 0, 0);
}

// ---- prep_a: u = user@Wu^T+bu, qv = query@Wq^T+bq  (64 blocks x 256) ------
__global__ void prep_a(const float* __restrict__ user, const float* __restrict__ query,
                       const float* __restrict__ Wu, const float* __restrict__ bu,
                       const float* __restrict__ Wq, const float* __restrict__ bq,
                       float* __restrict__ wf) {
  const int og = threadIdx.x >> 5, ln = threadIdx.x & 31;
  const int o = blockIdx.x * 8 + og;        // 0..511
  const int isq = o >> 8, j = o & 255;
  const float* Wrow = (isq ? Wq : Wu) + (size_t)j * 768;
  const float* vec = isq ? query : user;
  float p = 0.f;
  #pragma unroll
  for (int i = 0; i < 24; ++i) { int d = ln * 24 + i; p = fmaf(Wrow[d], vec[d], p); }
  #pragma unroll
  for (int off = 16; off; off >>= 1) p += __shfl_xor(p, off);
  if (ln == 0) wf[o] = p + (isq ? bq[j] : bu[j]);
}

// ---- prep_b: k0,k1,v0,v1 from ctx={u,qv}  (128 blocks x 256) --------------
__global__ void prep_b(const float* __restrict__ ipw, const float* __restrict__ ipb,
                       float* __restrict__ wf) {
  const int og = threadIdx.x >> 5, ln = threadIdx.x & 31;
  const int o = blockIdx.x * 8 + og;        // 0..1023
  const int kv = o >> 9, cc = (o >> 8) & 1, j = o & 255;
  const int row = 256 + kv * 256 + j;
  const float* Wrow = ipw + (size_t)row * 256;
  const float* ctx = wf + cc * 256;
  float p = 0.f;
  #pragma unroll
  for (int i = 0; i < 8; ++i) { int d = ln * 8 + i; p = fmaf(Wrow[d], ctx[d], p); }
  #pragma unroll
  for (int off = 16; off; off >>= 1) p += __shfl_xor(p, off);
  if (ln == 0) wf[512 + o] = p + ipb[row];
}

// ---- prep_c: wsd, csd (blocks 0-3), base, delta (block 4)  (5 x 256) ------
__global__ void prep_c(const float* __restrict__ ipw, const float* __restrict__ ipb,
                       const float* __restrict__ opw, const float* __restrict__ opb,
                       float* __restrict__ wf) {
  const int t = threadIdx.x, b = blockIdx.x;
  if (b < 4) {
    const int h = b;
    float acc = 0.f;
    for (int d = 0; d < 64; ++d) {
      float kd = wf[512 + h * 64 + d] - wf[768 + h * 64 + d];
      acc = fmaf(ipw[(size_t)(h * 64 + d) * 256 + t], kd, acc);
    }
    wf[1536 + h * 256 + t] = 0.125f * acc;
    if (t == 0) {
      float cs = 0.f;
      for (int d = 0; d < 64; ++d)
        cs = fmaf(ipb[h * 64 + d], wf[512 + h * 64 + d] - wf[768 + h * 64 + d], cs);
      wf[3840 + h] = 0.125f * cs;
    }
  } else {
    const float* oprow = opw + (size_t)t * 256;
    float bse = 0.f;
    for (int i = 0; i < 256; ++i) bse = fmaf(oprow[i], wf[1280 + i], bse);
    wf[2560 + t] = bse + opb[t];
    #pragma unroll
    for (int h = 0; h < 4; ++h) {
      float dl = 0.f;
      for (int d = 0; d < 64; ++d)
        dl = fmaf(oprow[h * 64 + d], wf[1024 + h * 64 + d] - wf[1280 + h * 64 + d], dl);
      wf[2816 + h * 256 + t] = dl;
    }
  }
}

// ---- prep_w: Wl fp32 -> bf16, pre-swizzled B-fragment layout (96 x 256) ---
__global__ void prep_w(const float* __restrict__ Wl, unsigned int* __restrict__ Bs4) {
  const int tid = blockIdx.x * 256 + threadIdx.x;   // (kk*16+nt)*64+lane
  const int lane = tid & 63;
  const int ntk = tid >> 6;
  const int kk = ntk >> 4, nt = ntk & 15;
  const int k = kk * 32 + (lane >> 4) * 8;
  const int j = nt * 16 + (lane & 15);
  const float* src = Wl + (size_t)j * 768 + k;
  uint4 pk;
  pk.x = f2bf(src[0]) | (f2bf(src[1]) << 16);
  pk.y = f2bf(src[2]) | (f2bf(src[3]) << 16);
  pk.z = f2bf(src[4]) | (f2bf(src[5]) << 16);
  pk.w = f2bf(src[6]) | (f2bf(src[7]) << 16);
  ((uint4*)Bs4)[tid] = pk;
}

// ---- main: 64 rows/block, 4 column-split waves; A ring-3 + B-in-regs ------
// LDS: smem[24576] = A ring[3][8192]. Epilogue overlays (floats):
//   [0,1024) wsd  [1024,2048) delta  [2048,2304) base  [2304,2560) woa
//   [2560,2816) wo2  [2816,3072) bl  [3072,4096) psd_p[4][64][4]
//   [4096,4352) pr2_p[4][64]
__global__ __launch_bounds__(256, 3) void fused_main(
    const float* __restrict__ llm, const float* __restrict__ bl,
    const float* __restrict__ Wo, const float* __restrict__ bo,
    const float* __restrict__ wf, float* __restrict__ out) {

  __shared__ __align__(16) char smem[24576];
  __shared__ float csd_s[4];
  __shared__ float a_s[64][4];
  __shared__ float r2_s[64];
  __shared__ float p2_s[4][64];

  const int t = threadIdx.x;
  const int w = t >> 6, l = t & 63, g = l >> 4, c = l & 15;
  const int m0 = blockIdx.x * 64;
  const char* BsB = (const char*)(wf + 4096);

  // stage A K-tile kk into ring slot: 8 KB via 2 gl_lds per wave.
  auto stageA = [&](int slot, int kk) {
    char* abase = smem + slot * 8192 + w * 1024;
    #pragma unroll
    for (int r = 0; r < 2; ++r) {
      const int chunk = r * 256 + w * 64 + l;        // 16B-chunk index
      const int row = chunk >> 3;                    // 0..63
      const int cb = (chunk & 7) * 16;               // physical col-byte
      const int cl = cb ^ ((row & 7) << 4);          // inverse-swizzled source
      const char* gp = (const char*)(llm + (size_t)(m0 + row) * 768 + kk * 32) + cl;
      gl_lds16(gp, abase + r * 4096);
    }
  };

  uint4 b0[4], b1[4];

  // prologue: FIFO per wave = [A0(2), B0(4), A1(2)]
  stageA(0, 0);
  {
    const char* gb = BsB + (size_t)l * 16;
    #pragma unroll
    for (int cf = 0; cf < 4; ++cf)
      b0[cf] = *(const uint4*)(gb + (w * 4 + cf) * 1024);
  }
  stageA(1, 1);

  f32x4 acc[4][4] = {};
  const int sx = (c & 7) << 4;

  auto step = [&](int kk, int slot, int nslot2, uint4* use, uint4* fill) {
    // loop-top outstanding: [B(kk):4, A(kk+1):2] -> leave A(kk+1) flying
    if (kk < 23) { VMCNT(2); } else { VMCNT(0); }
    __builtin_amdgcn_s_barrier();               // A(kk) visible; slot nslot2 free
    __builtin_amdgcn_sched_barrier(0);          // pin issues below barrier
    if (kk < 23) {
      const char* gb = BsB + (size_t)(kk + 1) * 16384 + (size_t)l * 16;
      #pragma unroll
      for (int cf = 0; cf < 4; ++cf)
        fill[cf] = *(const uint4*)(gb + (w * 4 + cf) * 1024);
    }
    if (kk < 22) stageA(nslot2, kk + 2);
    const char* ab = smem + slot * 8192;
    #pragma unroll
    for (int rf = 0; rf < 4; ++rf) {
      const char* rp = ab + (rf * 16 + c) * 128;
      const float4 fa = *(const float4*)(rp + ((g * 32) ^ sx));
      const float4 fb = *(const float4*)(rp + ((g * 32 + 16) ^ sx));
      uint4 pk;
      pk.x = f2bf(fa.x) | (f2bf(fa.y) << 16);
      pk.y = f2bf(fa.z) | (f2bf(fa.w) << 16);
      pk.z = f2bf(fb.x) | (f2bf(fb.y) << 16);
      pk.w = f2bf(fb.z) | (f2bf(fb.w) << 16);
      const bf16x8 afr = __builtin_bit_cast(bf16x8, pk);
      #pragma unroll
      for (int cf = 0; cf < 4; ++cf)
        acc[rf][cf] = __builtin_amdgcn_mfma_f32_16x16x32_bf16(
            afr, __builtin_bit_cast(bf16x8, use[cf]), acc[rf][cf], 0, 0, 0);
    }
  };

  for (int kk = 0; kk < 24; kk += 2) {
    const int s0 = kk % 3;
    const int s1 = (s0 + 1 == 3) ? 0 : s0 + 1;
    const int s2 = (s1 + 1 == 3) ? 0 : s1 + 1;
    step(kk,     s0, s2, b0, b1);   // stages A(kk+2) -> slot s2
    step(kk + 1, s1, s0, b1, b0);   // stages A(kk+3) -> slot s0
  }

  __syncthreads();   // K-loop fully done before smem reuse

  // ---- epilogue tables + partials overlay ----
  float* smf = (float*)smem;
  float* wsd_s  = smf;           // [1024]
  float* delta_s = smf + 1024;   // [1024]
  float* base_s = smf + 2048;    // [256]
  float* woa_s  = smf + 2304;    // [256]
  float* wo2_s  = smf + 2560;    // [256]
  float* bl_s   = smf + 2816;    // [256]
  float* psd_p  = smf + 3072;    // [4][64][4]
  float* pr2_p  = smf + 4096;    // [4][64]
  for (int i = t; i < 1024; i += 256) { wsd_s[i] = wf[1536 + i]; delta_s[i] = wf[2816 + i]; }
  base_s[t] = wf[2560 + t];
  woa_s[t] = Wo[t];
  wo2_s[t] = Wo[256 + t];
  bl_s[t] = bl[t];
  if (t < 4) csd_s[t] = wf[3840 + t];
  __syncthreads();

  // Pass 1 (column-split): per-wave partial sdiff/relu-dot over its 64 cols,
  // 16-lane shuffle reduce, per-rf to limit register pressure.
  // C frag (rf,cf): row = rf*16 + g*4 + j, col = w*64 + cf*16 + c.
  #pragma unroll
  for (int rf = 0; rf < 4; ++rf) {
    float psd[4][4] = {};
    float pr2[4] = {};
    #pragma unroll
    for (int cf = 0; cf < 4; ++cf) {
      const int col = w * 64 + cf * 16 + c;
      const float w0 = wsd_s[col], w1 = wsd_s[256 + col],
                  w2 = wsd_s[512 + col], w3 = wsd_s[768 + col];
      const float wo = wo2_s[col], bb2 = bl_s[col];
      #pragma unroll
      for (int j = 0; j < 4; ++j) {
        const float x = acc[rf][cf][j] + bb2;
        psd[j][0] = fmaf(x, w0, psd[j][0]);
        psd[j][1] = fmaf(x, w1, psd[j][1]);
        psd[j][2] = fmaf(x, w2, psd[j][2]);
        psd[j][3] = fmaf(x, w3, psd[j][3]);
        pr2[j] = fmaf(fmaxf(x, 0.f), wo, pr2[j]);
      }
    }
    #pragma unroll
    for (int off = 8; off; off >>= 1) {
      #pragma unroll
      for (int j = 0; j < 4; ++j) {
        #pragma unroll
        for (int h = 0; h < 4; ++h) psd[j][h] += __shfl_xor(psd[j][h], off);
        pr2[j] += __shfl_xor(pr2[j], off);
      }
    }
    if (c == 0) {
      #pragma unroll
      for (int j = 0; j < 4; ++j) {
        const int row = rf * 16 + g * 4 + j;
        #pragma unroll
        for (int h = 0; h < 4; ++h) psd_p[w * 256 + row * 4 + h] = psd[j][h];
        pr2_p[w * 64 + row] = pr2[j];
      }
    }
  }
  __syncthreads();

  // combine partials across 4 waves -> gates + r2
  if (t < 64) {
    #pragma unroll
    for (int h = 0; h < 4; ++h) {
      float sd = csd_s[h];
      #pragma unroll
      for (int ww = 0; ww < 4; ++ww) sd += psd_p[ww * 256 + t * 4 + h];
      a_s[t][h] = 1.f / (1.f + __expf(-sd));
    }
    float rr = 0.f;
    #pragma unroll
    for (int ww = 0; ww < 4; ++ww) rr += pr2_p[ww * 64 + t];
    r2_s[t] = rr;
  }
  __syncthreads();

  // Pass 2: attended reconstruction + relu-dot, 4 col-quarters x 64 rows.
  {
    const int r = t & 63, q = t >> 6;
    const float a0 = a_s[r][0], a1 = a_s[r][1], a2 = a_s[r][2], a3 = a_s[r][3];
    float p = 0.f;
    const int j0 = q * 64;
    #pragma unroll 4
    for (int j = j0; j < j0 + 64; ++j) {
      float att = base_s[j];
      att = fmaf(a0, delta_s[j], att);
      att = fmaf(a1, delta_s[256 + j], att);
      att = fmaf(a2, delta_s[512 + j], att);
      att = fmaf(a3, delta_s[768 + j], att);
      p = fmaf(fmaxf(att, 0.f), woa_s[j], p);
    }
    p2_s[q][r] = p;
  }
  __syncthreads();
  if (t < 64)
    out[m0 + t] = p2_s[0][t] + p2_s[1][t] + p2_s[2][t] + p2_s[3][t] + r2_s[t] + bo[0];
}

// ---------------------------------------------------------------------------
extern "C" void kernel_launch(void* const* d_in, const int* in_sizes, int n_in,
                              void* d_out, int out_size, void* d_ws, size_t ws_size,
                              hipStream_t stream) {
  const float* user  = (const float*)d_in[0];
  const float* query = (const float*)d_in[1];
  const float* llm   = (const float*)d_in[2];
  const float* Wu    = (const float*)d_in[3];
  const float* bu    = (const float*)d_in[4];
  const float* Wq    = (const float*)d_in[5];
  const float* bq    = (const float*)d_in[6];
  const float* Wl    = (const float*)d_in[7];
  const float* bl    = (const float*)d_in[8];
  const float* ipw   = (const float*)d_in[9];
  const float* ipb   = (const float*)d_in[10];
  const float* opw   = (const float*)d_in[11];
  const float* opb   = (const float*)d_in[12];
  const float* Wo    = (const float*)d_in[13];
  const float* bo    = (const float*)d_in[14];
  float* out = (float*)d_out;
  float* wf = (float*)d_ws;
  unsigned int* Bs4 = (unsigned int*)(wf + 4096);

  prep_a<<<64, 256, 0, stream>>>(user, query, Wu, bu, Wq, bq, wf);
  prep_w<<<96, 256, 0, stream>>>(Wl, Bs4);
  prep_b<<<128, 256, 0, stream>>>(ipw, ipb, wf);
  prep_c<<<5, 256, 0, stream>>>(ipw, ipb, opw, opb, wf);
  fused_main<<<131072 / 64, 256, 0, stream>>>(llm, bl, Wo, bo, wf, out);
}